// Round 5
// baseline (921.638 us; speedup 1.0000x reference)
//
#include <hip/hip_runtime.h>
#include <hip/hip_bf16.h>

#define N_NODES 20000
#define N_EDGES 640000
#define D 128
#define H 256

// MFMA fragment types (guide §3, compile-verified style on gfx950)
using bf16x8 = __attribute__((ext_vector_type(8))) short;
using f32x4  = __attribute__((ext_vector_type(4))) float;

__device__ __forceinline__ unsigned short f2bf(float f) {
  unsigned int u = __float_as_uint(f);
  unsigned int r = u + 0x7fffu + ((u >> 16) & 1u);
  return (unsigned short)(r >> 16);
}

// async global->LDS, 16B per lane; LDS dest = wave-uniform base + lane*16 (guide §5)
__device__ __forceinline__ void gload_lds16(const void* g, void* l) {
  __builtin_amdgcn_global_load_lds(
      (const __attribute__((address_space(1))) void*)g,
      (__attribute__((address_space(3))) void*)l, 16, 0, 0);
}

// ---------------- prep: agg zero, nf->bf16, fragment-order weights (edge), transposed (node) ----
// We1F frag layout: [(ks*16 + nt)*64 + lane]*8 + e  = We1[(ks*32+(lane>>4)*8+e)*256 + nt*16+(lane&15)]
// We2F frag layout: [(ks*8  + nt)*64 + lane]*8 + e  = We2[(ks*32+(lane>>4)*8+e)*128 + nt*16+(lane&15)]
__global__ __launch_bounds__(256) void prep_kernel(
    const float* __restrict__ nf, const int* __restrict__ dst,
    const float* __restrict__ We1, const float* __restrict__ We2,
    const float* __restrict__ Wn1, const float* __restrict__ Wn2,
    float* __restrict__ agg, unsigned short* __restrict__ nf_bf,
    unsigned short* __restrict__ We1F, unsigned short* __restrict__ We2F,
    unsigned short* __restrict__ Wn1T, unsigned short* __restrict__ Wn2T,
    int* __restrict__ deg) {
  int idx = blockIdx.x * 256 + threadIdx.x;
  if (idx < N_NODES * D) {
    agg[idx] = 0.f;
    nf_bf[idx] = f2bf(nf[idx]);
  }
  if (idx < N_EDGES) {
    atomicAdd(&deg[dst[idx]], 1);   // 640k int atomics: cheap
  }
  if (idx < 98304) {                        // We1F: 12 ks x 16 nt x 64 lane x 8 e
    int e = idx & 7, l = (idx >> 3) & 63, nt = (idx >> 9) & 15, ks = idx >> 13;
    int k = ks * 32 + (l >> 4) * 8 + e;
    int col = nt * 16 + (l & 15);
    We1F[idx] = f2bf(We1[k * 256 + col]);
  } else if (idx < 131072) {                // We2F: 8 ks x 8 nt x 64 x 8
    int j = idx - 98304;
    int e = j & 7, l = (j >> 3) & 63, nt = (j >> 9) & 7, ks = j >> 12;
    int k = ks * 32 + (l >> 4) * 8 + e;
    int col = nt * 16 + (l & 15);
    We2F[j] = f2bf(We2[k * 128 + col]);
  } else if (idx < 196608) {                // Wn1T [256,256] (node kernel, row-major-T)
    int j = idx - 131072; int n = j / 256, k = j % 256;
    Wn1T[j] = f2bf(Wn1[k * 256 + n]);
  } else if (idx < 229376) {                // Wn2T [128,256]
    int j = idx - 196608; int n = j / 256, k = j % 256;
    Wn2T[j] = f2bf(Wn2[k * 128 + n]);
  }
}

// ---------------- scan: single block exclusive prefix sum of deg -> cursor ----------------
__global__ __launch_bounds__(1024) void scan_kernel(const int* __restrict__ deg,
                                                    int* __restrict__ cursor) {
  __shared__ int sums[1024];
  const int t = threadIdx.x;
  const int base = t * 20;            // 1024*20 = 20480 >= 20000
  int local[20];
  int s = 0;
#pragma unroll
  for (int i = 0; i < 20; i++) {
    int p = base + i;
    int v = (p < N_NODES) ? deg[p] : 0;
    local[i] = s;                      // exclusive within thread
    s += v;
  }
  sums[t] = s;
  __syncthreads();
  for (int ofs = 1; ofs < 1024; ofs <<= 1) {
    int v = (t >= ofs) ? sums[t - ofs] : 0;
    __syncthreads();
    sums[t] += v;
    __syncthreads();
  }
  int ebase = sums[t] - s;             // exclusive base for this thread
#pragma unroll
  for (int i = 0; i < 20; i++) {
    int p = base + i;
    if (p < N_NODES) cursor[p] = ebase + local[i];
  }
}

// ---------------- fill: CSR column fill (eidx grouped by dst) ----------------
__global__ __launch_bounds__(256) void fill_kernel(const int* __restrict__ dst,
                                                   int* __restrict__ cursor,
                                                   int* __restrict__ eidx) {
  int e = blockIdx.x * 256 + threadIdx.x;
  if (e < N_EDGES) {
    int d = dst[e];
    int pos = atomicAdd(&cursor[d], 1);
    eidx[pos] = e;
  }
}

// ---------------- edge kernel: 64 dst-sorted edges/block, fused MLP + in-block seg-reduce ----------
// A-tile LDS: frag f = ks*4 + mt (ks 0..11, mt 0..3), bytes [f*1024, +1024) = lane*16 each.
// em_in k-order: ks 0..3 = ef, 4..7 = nf[src], 8..11 = nf[dst].
#define HS 264    // h LDS row stride (bf16): 256 + 8 pad (528 B)
#define CF 132    // C f32 LDS row stride (floats): 128 + 4 pad (528 B, overlays h)

__global__ __launch_bounds__(512, 6) void edge_kernel(
    const float* __restrict__ ef, const unsigned short* __restrict__ nf_bf,
    const int* __restrict__ src, const int* __restrict__ dst,
    const int* __restrict__ eidx,
    const unsigned short* __restrict__ We1F, const float* __restrict__ be1,
    const unsigned short* __restrict__ We2F, const float* __restrict__ be2,
    float* __restrict__ out_ef, float* __restrict__ agg) {
  __shared__ unsigned short smemA[64 * 384];   // 49152 B; h then C-f32 overlay after use
  __shared__ int smemE[64];
  __shared__ int smemD[64];
  unsigned short* hbuf = smemA;
  float* cbuf = (float*)smemA;

  const int tid  = threadIdx.x;
  const int lane = tid & 63;
  const int w    = tid >> 6;      // 0..7
  const int ln15 = lane & 15;
  const int q    = lane >> 4;
  const int wr   = w >> 2;        // 0..1  (32-row half)
  const int wc   = w & 3;         // 0..3  (64-col quarter of H)
  const int e0   = blockIdx.x * 64;

  // ---- stage: async gathers (dst-sorted edge ids via eidx) ----
  if (tid < 64) {
    int e = eidx[e0 + tid];
    smemE[tid] = e;
    smemD[tid] = dst[e];
  }
  {
#pragma unroll
    for (int i = 0; i < 2; i++) {
      int id = w * 2 + i;
      int ksub = id >> 2, mt = id & 3;
      int e = eidx[e0 + mt * 16 + ln15];
      int sidx = src[e];
      gload_lds16(&nf_bf[(size_t)sidx * 128 + ksub * 32 + q * 8],
                  &smemA[((4 + ksub) * 4 + mt) * 512]);
    }
#pragma unroll
    for (int i = 0; i < 2; i++) {
      int id = w * 2 + i;
      int ksub = id >> 2, mt = id & 3;
      int e = eidx[e0 + mt * 16 + ln15];
      int didx = dst[e];
      gload_lds16(&nf_bf[(size_t)didx * 128 + ksub * 32 + q * 8],
                  &smemA[((8 + ksub) * 4 + mt) * 512]);
    }
    // ef frags (f32 -> bf16 via VGPR): row gather of sorted edges
#pragma unroll
    for (int i = 0; i < 2; i++) {
      int id = w * 2 + i;
      int kse = id >> 2, mt = id & 3;
      int e = eidx[e0 + mt * 16 + ln15];
      const float* p = &ef[(size_t)e * 128 + kse * 32 + q * 8];
      float4 v0 = *(const float4*)p;
      float4 v1 = *(const float4*)(p + 4);
      uint4 o;
      o.x = (unsigned)f2bf(v0.x) | ((unsigned)f2bf(v0.y) << 16);
      o.y = (unsigned)f2bf(v0.z) | ((unsigned)f2bf(v0.w) << 16);
      o.z = (unsigned)f2bf(v1.x) | ((unsigned)f2bf(v1.y) << 16);
      o.w = (unsigned)f2bf(v1.z) | ((unsigned)f2bf(v1.w) << 16);
      *(uint4*)&smemA[(kse * 4 + mt) * 512 + lane * 8] = o;
    }
  }
  __syncthreads();   // drains vmcnt (global_load_lds) + lgkmcnt (ds_write)

  // ---- GEMM1: h[64,256] = relu(em @ We1 + be1); wave owns rows [32wr,+32) x cols [64wc,+64) ----
  f32x4 acc[2][4] = {};
#pragma unroll
  for (int ks = 0; ks < 12; ks++) {
    bf16x8 a[2], b[4];
#pragma unroll
    for (int m = 0; m < 2; m++)
      a[m] = *(const bf16x8*)&smemA[(ks * 4 + wr * 2 + m) * 512 + lane * 8];
#pragma unroll
    for (int nt = 0; nt < 4; nt++)
      b[nt] = *(const bf16x8*)&We1F[(size_t)((ks * 16 + wc * 4 + nt) * 64 + lane) * 8];
#pragma unroll
    for (int m = 0; m < 2; m++)
#pragma unroll
      for (int nt = 0; nt < 4; nt++)
        acc[m][nt] = __builtin_amdgcn_mfma_f32_16x16x32_bf16(a[m], b[nt], acc[m][nt], 0, 0, 0);
  }

  float bias1[4];
#pragma unroll
  for (int nt = 0; nt < 4; nt++) bias1[nt] = be1[wc * 64 + nt * 16 + ln15];

  __syncthreads();   // all A-frag reads done; safe to overlay h

  // C/D layout: col = lane&15, row = q*4 + reg
#pragma unroll
  for (int m = 0; m < 2; m++)
#pragma unroll
    for (int nt = 0; nt < 4; nt++)
#pragma unroll
      for (int r = 0; r < 4; r++) {
        float v = acc[m][nt][r] + bias1[nt];
        v = v > 0.f ? v : 0.f;
        hbuf[(wr * 32 + m * 16 + q * 4 + r) * HS + wc * 64 + nt * 16 + ln15] = f2bf(v);
      }
  __syncthreads();

  // ---- GEMM2: out[64,128] = h @ We2 + be2; wave owns rows [32wr,+32) x cols [32wc,+32) ----
  f32x4 acc2[2][2] = {};
#pragma unroll
  for (int ks = 0; ks < 8; ks++) {
    bf16x8 a2[2], b2[2];
#pragma unroll
    for (int m = 0; m < 2; m++)
      a2[m] = *(const bf16x8*)&hbuf[(wr * 32 + m * 16 + ln15) * HS + ks * 32 + q * 8];
#pragma unroll
    for (int nt = 0; nt < 2; nt++)
      b2[nt] = *(const bf16x8*)&We2F[(size_t)((ks * 8 + wc * 2 + nt) * 64 + lane) * 8];
#pragma unroll
    for (int m = 0; m < 2; m++)
#pragma unroll
      for (int nt = 0; nt < 2; nt++)
        acc2[m][nt] = __builtin_amdgcn_mfma_f32_16x16x32_bf16(a2[m], b2[nt], acc2[m][nt], 0, 0, 0);
  }

  float bias2[2];
#pragma unroll
  for (int nt = 0; nt < 2; nt++) bias2[nt] = be2[wc * 32 + nt * 16 + ln15];

  __syncthreads();   // all h reads done; safe to overlay C f32

  // ---- epilogue: scatter-write updated_ef rows + spill C f32 to LDS for seg-reduce ----
#pragma unroll
  for (int m = 0; m < 2; m++) {
#pragma unroll
    for (int r = 0; r < 4; r++) {
      int row = wr * 32 + m * 16 + q * 4 + r;
      int e = smemE[row];
#pragma unroll
      for (int nt = 0; nt < 2; nt++) {
        int col = wc * 32 + nt * 16 + ln15;
        float v = acc2[m][nt][r] + bias2[nt];
        out_ef[(size_t)e * 128 + col] = v;
        cbuf[row * CF + col] = v;
      }
    }
  }
  __syncthreads();

  // ---- segmented reduce over dst-sorted rows: one atomicAdd per (segment x col) ----
  {
    const int col = tid & 127;
    const int r0  = (tid >> 7) * 16;     // 4 chunks of 16 rows
    float s = 0.f;
    int dcur = smemD[r0];
    for (int r = r0; r < r0 + 16; ++r) {
      int dn = smemD[r];                 // wave-uniform -> uniform branch
      float v = cbuf[r * CF + col];
      if (dn != dcur) {
        atomicAdd(&agg[(size_t)dcur * 128 + col], s);
        s = 0.f; dcur = dn;
      }
      s += v;
    }
    atomicAdd(&agg[(size_t)dcur * 128 + col], s);
  }
}

// ---------------- node kernel: stage [agg(f32) | nf_bf], fused 2-layer MLP ----------------
__global__ __launch_bounds__(256, 3) void node_kernel(
    const float* __restrict__ agg, const unsigned short* __restrict__ nf_bf,
    const unsigned short* __restrict__ Wn1T, const float* __restrict__ bn1,
    const unsigned short* __restrict__ Wn2T, const float* __restrict__ bn2,
    float* __restrict__ out_nf) {
  __shared__ unsigned short smem[64 * HS];   // 33792 B; h overlaid after barrier

  const int tid  = threadIdx.x;
  const int lane = tid & 63;
  const int wave = tid >> 6;
  const int ln15 = lane & 15;
  const int q    = lane >> 4;
  const int n0   = blockIdx.x * 64;

  const int nb1 = wave * 64;
  const int nb2 = wave * 32;

  float bias1[4];
#pragma unroll
  for (int nt = 0; nt < 4; nt++) bias1[nt] = bn1[nb1 + nt * 16 + ln15];

  // ---- stage nm_in = [agg | nf] ----
  {
    const float4* agg4 = (const float4*)agg;
#pragma unroll
    for (int i = 0; i < 8; i++) {
      int flat = tid + 256 * i;            // 2048 float4 tasks
      int row = flat >> 5, c4 = flat & 31;
      int node = n0 + row;
      float4 v = make_float4(0.f, 0.f, 0.f, 0.f);
      if (node < N_NODES) v = agg4[(size_t)node * 32 + c4];
      ushort4 o = { f2bf(v.x), f2bf(v.y), f2bf(v.z), f2bf(v.w) };
      *(ushort4*)&smem[row * HS + c4 * 4] = o;
    }
#pragma unroll
    for (int i = 0; i < 4; i++) {
      int flat = tid + 256 * i;
      int row = flat >> 4, seg = flat & 15;
      int node = n0 + row;
      uint4 vn = make_uint4(0u, 0u, 0u, 0u);
      if (node < N_NODES) vn = *(const uint4*)&nf_bf[(size_t)node * 128 + seg * 8];
      *(uint4*)&smem[row * HS + 128 + seg * 8] = vn;
    }
  }
  __syncthreads();

  // ---- layer 1: K=256 ----
  f32x4 acc[4][4] = {};
#pragma unroll
  for (int ks = 0; ks < 8; ks++) {
    const int kc = ks * 32 + q * 8;
    bf16x8 a[4], b[4];
#pragma unroll
    for (int mt = 0; mt < 4; mt++)
      a[mt] = *(const bf16x8*)&smem[(mt * 16 + ln15) * HS + kc];
#pragma unroll
    for (int nt = 0; nt < 4; nt++)
      b[nt] = *(const bf16x8*)&Wn1T[(size_t)(nb1 + nt * 16 + ln15) * 256 + kc];
#pragma unroll
    for (int mt = 0; mt < 4; mt++)
#pragma unroll
      for (int nt = 0; nt < 4; nt++)
        acc[mt][nt] = __builtin_amdgcn_mfma_f32_16x16x32_bf16(a[mt], b[nt], acc[mt][nt], 0, 0, 0);
  }

  float bias2[2];
#pragma unroll
  for (int nt = 0; nt < 2; nt++) bias2[nt] = bn2[nb2 + nt * 16 + ln15];

  __syncthreads();

#pragma unroll
  for (int mt = 0; mt < 4; mt++)
#pragma unroll
    for (int nt = 0; nt < 4; nt++)
#pragma unroll
      for (int r = 0; r < 4; r++) {
        float v = acc[mt][nt][r] + bias1[nt];
        v = v > 0.f ? v : 0.f;
        smem[(mt * 16 + q * 4 + r) * HS + nb1 + nt * 16 + ln15] = f2bf(v);
      }
  __syncthreads();

  // ---- layer 2: K=256, N=128 ----
  f32x4 acc2[4][2] = {};
#pragma unroll
  for (int ks = 0; ks < 8; ks++) {
    const int kc = ks * 32 + q * 8;
    bf16x8 a2[4], b2[2];
#pragma unroll
    for (int mt = 0; mt < 4; mt++)
      a2[mt] = *(const bf16x8*)&smem[(mt * 16 + ln15) * HS + kc];
#pragma unroll
    for (int nt = 0; nt < 2; nt++)
      b2[nt] = *(const bf16x8*)&Wn2T[(size_t)(nb2 + nt * 16 + ln15) * 256 + kc];
#pragma unroll
    for (int mt = 0; mt < 4; mt++)
#pragma unroll
      for (int nt = 0; nt < 2; nt++)
        acc2[mt][nt] = __builtin_amdgcn_mfma_f32_16x16x32_bf16(a2[mt], b2[nt], acc2[mt][nt], 0, 0, 0);
  }

#pragma unroll
  for (int mt = 0; mt < 4; mt++) {
#pragma unroll
    for (int r = 0; r < 4; r++) {
      int row = mt * 16 + q * 4 + r;
      int node = n0 + row;
      if (node < N_NODES) {
#pragma unroll
        for (int nt = 0; nt < 2; nt++) {
          int col = nb2 + nt * 16 + ln15;
          out_nf[(size_t)node * 128 + col] = acc2[mt][nt][r] + bias2[nt];
        }
      }
    }
  }
}

extern "C" void kernel_launch(void* const* d_in, const int* in_sizes, int n_in,
                              void* d_out, int out_size, void* d_ws, size_t ws_size,
                              hipStream_t stream) {
  const float* nf  = (const float*)d_in[0];
  const float* ef  = (const float*)d_in[1];
  const int*   src = (const int*)d_in[2];
  const int*   dst = (const int*)d_in[3];
  const float* We1 = (const float*)d_in[4];
  const float* be1 = (const float*)d_in[5];
  const float* We2 = (const float*)d_in[6];
  const float* be2 = (const float*)d_in[7];
  const float* Wn1 = (const float*)d_in[8];
  const float* bn1 = (const float*)d_in[9];
  const float* Wn2 = (const float*)d_in[10];
  const float* bn2 = (const float*)d_in[11];

  float* out_nf = (float*)d_out;                    // updated_nf first (return order)
  float* out_ef = out_nf + (size_t)N_NODES * D;     // then updated_ef

  char* ws = (char*)d_ws;
  unsigned short* nf_bf  = (unsigned short*)ws;                  // 5,120,000 B
  unsigned short* We1F   = (unsigned short*)(ws + 5120000);      //   196,608 B
  unsigned short* We2F   = (unsigned short*)(ws + 5316608);      //    65,536 B
  unsigned short* Wn1T   = (unsigned short*)(ws + 5382144);      //   131,072 B
  unsigned short* Wn2T   = (unsigned short*)(ws + 5513216);      //    65,536 B
  int*            deg    = (int*)(ws + 5578752);                 //    80,000 B
  int*            cursor = (int*)(ws + 5658752);                 //    80,000 B
  int*            eidx   = (int*)(ws + 5738752);                 // 2,560,000 B
  float*          agg    = (float*)(ws + 8298752);               // 10,240,000 B (end ~18.5 MB)

  hipMemsetAsync(deg, 0, N_NODES * sizeof(int), stream);
  prep_kernel<<<10000, 256, 0, stream>>>(nf, dst, We1, We2, Wn1, Wn2,
                                         agg, nf_bf, We1F, We2F, Wn1T, Wn2T, deg);
  scan_kernel<<<1, 1024, 0, stream>>>(deg, cursor);
  fill_kernel<<<N_EDGES / 256, 256, 0, stream>>>(dst, cursor, eidx);
  edge_kernel<<<N_EDGES / 64, 512, 0, stream>>>(ef, nf_bf, src, dst, eidx,
                                                We1F, be1, We2F, be2, out_ef, agg);
  node_kernel<<<(N_NODES + 63) / 64, 256, 0, stream>>>(agg, nf_bf,
                                                       Wn1T, bn1, Wn2T, bn2, out_nf);
}

// Round 8
// 869.726 us; speedup vs baseline: 1.0597x; 1.0597x over previous
//
#include <hip/hip_runtime.h>
#include <hip/hip_bf16.h>

#define N_NODES 20000
#define N_EDGES 640000
#define D 128
#define H 256

// MFMA fragment types (guide §3, compile-verified style on gfx950)
using bf16x8 = __attribute__((ext_vector_type(8))) short;
using f32x4  = __attribute__((ext_vector_type(4))) float;

__device__ __forceinline__ unsigned short f2bf(float f) {
  unsigned int u = __float_as_uint(f);
  unsigned int r = u + 0x7fffu + ((u >> 16) & 1u);
  return (unsigned short)(r >> 16);
}
__device__ __forceinline__ float bf2f(unsigned short u) {
  return __uint_as_float(((unsigned int)u) << 16);
}
// packed bf16x2 + bf16x2 -> bf16x2 (f32 add, one rounding)
__device__ __forceinline__ unsigned int pksum(unsigned int a, unsigned int b) {
  float lo = bf2f((unsigned short)(a & 0xffff)) + bf2f((unsigned short)(b & 0xffff));
  float hi = bf2f((unsigned short)(a >> 16))    + bf2f((unsigned short)(b >> 16));
  return (unsigned int)f2bf(lo) | ((unsigned int)f2bf(hi) << 16);
}

// async global->LDS, 16B per lane; LDS dest = wave-uniform base + lane*16 (guide §5)
__device__ __forceinline__ void gload_lds16(const void* g, void* l) {
  __builtin_amdgcn_global_load_lds(
      (const __attribute__((address_space(1))) void*)g,
      (__attribute__((address_space(3))) void*)l, 16, 0, 0);
}

// ---------------- prep: nf->bf16, fragment-order weights (edge), transposed (node), histogram ----
// We1F frag layout: [(ks*16 + nt)*64 + lane]*8 + e  = We1[(ks*32+(lane>>4)*8+e)*256 + nt*16+(lane&15)]
// We2F frag layout: [(ks*8  + nt)*64 + lane]*8 + e  = We2[(ks*32+(lane>>4)*8+e)*128 + nt*16+(lane&15)]
__global__ __launch_bounds__(256) void prep_kernel(
    const float* __restrict__ nf, const int* __restrict__ dst,
    const float* __restrict__ We1, const float* __restrict__ We2,
    const float* __restrict__ Wn1, const float* __restrict__ Wn2,
    unsigned short* __restrict__ nf_bf, unsigned short* __restrict__ We1F,
    unsigned short* __restrict__ We2F, unsigned short* __restrict__ Wn1T,
    unsigned short* __restrict__ Wn2T, int* __restrict__ deg) {
  int idx = blockIdx.x * 256 + threadIdx.x;
  if (idx < N_NODES * D) {
    nf_bf[idx] = f2bf(nf[idx]);
  }
  if (idx < N_EDGES) {
    atomicAdd(&deg[dst[idx]], 1);   // 640k int atomics: cheap
  }
  if (idx < 98304) {                        // We1F: 12 ks x 16 nt x 64 lane x 8 e
    int e = idx & 7, l = (idx >> 3) & 63, nt = (idx >> 9) & 15, ks = idx >> 13;
    int k = ks * 32 + (l >> 4) * 8 + e;
    int col = nt * 16 + (l & 15);
    We1F[idx] = f2bf(We1[k * 256 + col]);
  } else if (idx < 131072) {                // We2F: 8 ks x 8 nt x 64 x 8
    int j = idx - 98304;
    int e = j & 7, l = (j >> 3) & 63, nt = (j >> 9) & 7, ks = j >> 12;
    int k = ks * 32 + (l >> 4) * 8 + e;
    int col = nt * 16 + (l & 15);
    We2F[j] = f2bf(We2[k * 128 + col]);
  } else if (idx < 196608) {                // Wn1T [256,256] (node kernel, row-major-T)
    int j = idx - 131072; int n = j / 256, k = j % 256;
    Wn1T[j] = f2bf(Wn1[k * 256 + n]);
  } else if (idx < 229376) {                // Wn2T [128,256]
    int j = idx - 196608; int n = j / 256, k = j % 256;
    Wn2T[j] = f2bf(Wn2[k * 128 + n]);
  }
}

// ---------------- scan: single block exclusive prefix sum of deg -> cursor ----------------
__global__ __launch_bounds__(1024) void scan_kernel(const int* __restrict__ deg,
                                                    int* __restrict__ cursor) {
  __shared__ int sums[1024];
  const int t = threadIdx.x;
  const int base = t * 20;            // 1024*20 = 20480 >= 20000
  int local[20];
  int s = 0;
#pragma unroll
  for (int i = 0; i < 20; i++) {
    int p = base + i;
    int v = (p < N_NODES) ? deg[p] : 0;
    local[i] = s;                      // exclusive within thread
    s += v;
  }
  sums[t] = s;
  __syncthreads();
  for (int ofs = 1; ofs < 1024; ofs <<= 1) {
    int v = (t >= ofs) ? sums[t - ofs] : 0;
    __syncthreads();
    sums[t] += v;
    __syncthreads();
  }
  int ebase = sums[t] - s;             // exclusive base for this thread
#pragma unroll
  for (int i = 0; i < 20; i++) {
    int p = base + i;
    if (p < N_NODES) cursor[p] = ebase + local[i];
  }
}

// ---------------- fill: CSR column fill. After this, cursor[n] == inclusive prefix ----------------
__global__ __launch_bounds__(256) void fill_kernel(const int* __restrict__ dst,
                                                   int* __restrict__ cursor,
                                                   int* __restrict__ eidx) {
  int e = blockIdx.x * 256 + threadIdx.x;
  if (e < N_EDGES) {
    int d = dst[e];
    int pos = atomicAdd(&cursor[d], 1);
    eidx[pos] = e;
  }
}

// ---------------- pgemm: per-node partial products Ps = nf@Wb, Pd = nf@Wc + be1 ----------------
// A-tile frag order: frag f = ks*4+mt (ks 0..3, K=128); B from We1F global-ks 4..7 (Wb), 8..11 (Wc).
__global__ __launch_bounds__(512, 4) void pgemm_kernel(
    const unsigned short* __restrict__ nf_bf, const unsigned short* __restrict__ We1F,
    const float* __restrict__ be1,
    unsigned short* __restrict__ Ps, unsigned short* __restrict__ Pd) {
  __shared__ unsigned short smem[16 * 512];   // 16 frags x 1KB

  const int tid  = threadIdx.x;
  const int lane = tid & 63;
  const int w    = tid >> 6;
  const int ln15 = lane & 15;
  const int q    = lane >> 4;
  const int wr   = w >> 2;
  const int wc   = w & 3;
  const int n0   = blockIdx.x * 64;

#pragma unroll
  for (int i = 0; i < 2; i++) {
    int id = w * 2 + i;
    int ksub = id >> 2, mt = id & 3;
    int node = n0 + mt * 16 + ln15;
    if (node >= N_NODES) node = N_NODES - 1;    // clamp (garbage rows unwritten)
    gload_lds16(&nf_bf[(size_t)node * 128 + ksub * 32 + q * 8],
                &smem[(ksub * 4 + mt) * 512]);
  }
  __syncthreads();

  f32x4 accs[2][4] = {};
  f32x4 accd[2][4] = {};
#pragma unroll
  for (int ks = 0; ks < 4; ks++) {
    bf16x8 a[2], bs[4], bd[4];
#pragma unroll
    for (int m = 0; m < 2; m++)
      a[m] = *(const bf16x8*)&smem[(ks * 4 + wr * 2 + m) * 512 + lane * 8];
#pragma unroll
    for (int nt = 0; nt < 4; nt++) {
      bs[nt] = *(const bf16x8*)&We1F[(size_t)(((4 + ks) * 16 + wc * 4 + nt) * 64 + lane) * 8];
      bd[nt] = *(const bf16x8*)&We1F[(size_t)(((8 + ks) * 16 + wc * 4 + nt) * 64 + lane) * 8];
    }
#pragma unroll
    for (int m = 0; m < 2; m++)
#pragma unroll
      for (int nt = 0; nt < 4; nt++) {
        accs[m][nt] = __builtin_amdgcn_mfma_f32_16x16x32_bf16(a[m], bs[nt], accs[m][nt], 0, 0, 0);
        accd[m][nt] = __builtin_amdgcn_mfma_f32_16x16x32_bf16(a[m], bd[nt], accd[m][nt], 0, 0, 0);
      }
  }

#pragma unroll
  for (int m = 0; m < 2; m++) {
#pragma unroll
    for (int r = 0; r < 4; r++) {
      int node = n0 + wr * 32 + m * 16 + q * 4 + r;
      if (node < N_NODES) {
#pragma unroll
        for (int nt = 0; nt < 4; nt++) {
          int col = wc * 64 + nt * 16 + ln15;
          Ps[(size_t)node * 256 + col] = f2bf(accs[m][nt][r]);
          Pd[(size_t)node * 256 + col] = f2bf(accd[m][nt][r] + be1[col]);
        }
      }
    }
  }
}

// ---------------- edge kernel: 64 edges/block, K=128 GEMM1 + Psum add, 2 barriers ----------------
// efF frags: f = ks*4+mt (ks 0..3), 1KB each. pbuf: Psum bf16 [64][264], h overlays in place.
#define HS 264    // row stride (bf16): 256 + 8 pad (528 B)

__global__ __launch_bounds__(512, 6) void edge_kernel(
    const float* __restrict__ ef,
    const unsigned short* __restrict__ Ps, const unsigned short* __restrict__ Pd,
    const int* __restrict__ src, const int* __restrict__ dst,
    const unsigned short* __restrict__ We1F,
    const unsigned short* __restrict__ We2F, const float* __restrict__ be2,
    float* __restrict__ out_ef) {
  __shared__ unsigned short smem[16 * 512 + 64 * HS];   // 16384 + 33792 = 50176 B
  unsigned short* efF  = smem;            // 8192 shorts
  unsigned short* pbuf = smem + 8192;     // [64][HS] bf16: Psum, then h in place

  const int tid  = threadIdx.x;
  const int lane = tid & 63;
  const int w    = tid >> 6;      // 0..7
  const int ln15 = lane & 15;
  const int q    = lane >> 4;
  const int wr   = w >> 2;        // 0..1  (32-row half)
  const int wc   = w & 3;         // 0..3  (64-col quarter of H)
  const int e0   = blockIdx.x * 64;

  // ---- stage: ef frags (f32->bf16) + Psum rows (Ps[src]+Pd[dst], L3-resident tables) ----
  {
#pragma unroll
    for (int i = 0; i < 2; i++) {
      int id = w * 2 + i;                 // 0..15 = (kse 0..3) x (mt 0..3)
      int kse = id >> 2, mt = id & 3;
      const float* p = &ef[(size_t)(e0 + mt * 16 + ln15) * 128 + kse * 32 + q * 8];
      float4 v0 = *(const float4*)p;
      float4 v1 = *(const float4*)(p + 4);
      uint4 o;
      o.x = (unsigned)f2bf(v0.x) | ((unsigned)f2bf(v0.y) << 16);
      o.y = (unsigned)f2bf(v0.z) | ((unsigned)f2bf(v0.w) << 16);
      o.z = (unsigned)f2bf(v1.x) | ((unsigned)f2bf(v1.y) << 16);
      o.w = (unsigned)f2bf(v1.z) | ((unsigned)f2bf(v1.w) << 16);
      *(uint4*)&efF[(kse * 4 + mt) * 512 + lane * 8] = o;
    }
    // Psum: 8 threads per row, 32 cols (64B) each
    int prow = tid >> 3, seg = tid & 7;
    int e = e0 + prow;
    int s = src[e];
    int d = dst[e];
    const uint4* ps4 = (const uint4*)&Ps[(size_t)s * 256 + seg * 32];
    const uint4* pd4 = (const uint4*)&Pd[(size_t)d * 256 + seg * 32];
#pragma unroll
    for (int i = 0; i < 4; i++) {
      uint4 a = ps4[i], b = pd4[i];
      uint4 o;
      o.x = pksum(a.x, b.x);
      o.y = pksum(a.y, b.y);
      o.z = pksum(a.z, b.z);
      o.w = pksum(a.w, b.w);
      *(uint4*)&pbuf[prow * HS + seg * 32 + i * 8] = o;
    }
  }
  __syncthreads();

  // ---- GEMM1: acc = ef @ Wa (K=128); wave owns rows [32wr,+32) x cols [64wc,+64) ----
  f32x4 acc[2][4] = {};
#pragma unroll
  for (int ks = 0; ks < 4; ks++) {
    bf16x8 a[2], b[4];
#pragma unroll
    for (int m = 0; m < 2; m++)
      a[m] = *(const bf16x8*)&efF[(ks * 4 + wr * 2 + m) * 512 + lane * 8];
#pragma unroll
    for (int nt = 0; nt < 4; nt++)
      b[nt] = *(const bf16x8*)&We1F[(size_t)((ks * 16 + wc * 4 + nt) * 64 + lane) * 8];
#pragma unroll
    for (int m = 0; m < 2; m++)
#pragma unroll
      for (int nt = 0; nt < 4; nt++)
        acc[m][nt] = __builtin_amdgcn_mfma_f32_16x16x32_bf16(a[m], b[nt], acc[m][nt], 0, 0, 0);
  }

  // ---- h = relu(acc + Psum) in place (per-wave-disjoint region: no barrier needed) ----
  // C/D layout: col = lane&15, row = q*4 + reg
#pragma unroll
  for (int m = 0; m < 2; m++)
#pragma unroll
    for (int nt = 0; nt < 4; nt++)
#pragma unroll
      for (int r = 0; r < 4; r++) {
        int idx = (wr * 32 + m * 16 + q * 4 + r) * HS + wc * 64 + nt * 16 + ln15;
        float v = acc[m][nt][r] + bf2f(pbuf[idx]);
        v = v > 0.f ? v : 0.f;
        pbuf[idx] = f2bf(v);
      }
  __syncthreads();

  // ---- GEMM2: out[64,128] = h @ We2 + be2; wave owns rows [32wr,+32) x cols [32wc,+32) ----
  f32x4 acc2[2][2] = {};
#pragma unroll
  for (int ks = 0; ks < 8; ks++) {
    bf16x8 a2[2], b2[2];
#pragma unroll
    for (int m = 0; m < 2; m++)
      a2[m] = *(const bf16x8*)&pbuf[(wr * 32 + m * 16 + ln15) * HS + ks * 32 + q * 8];
#pragma unroll
    for (int nt = 0; nt < 2; nt++)
      b2[nt] = *(const bf16x8*)&We2F[(size_t)((ks * 8 + wc * 2 + nt) * 64 + lane) * 8];
#pragma unroll
    for (int m = 0; m < 2; m++)
#pragma unroll
      for (int nt = 0; nt < 2; nt++)
        acc2[m][nt] = __builtin_amdgcn_mfma_f32_16x16x32_bf16(a2[m], b2[nt], acc2[m][nt], 0, 0, 0);
  }

  float bias2[2];
#pragma unroll
  for (int nt = 0; nt < 2; nt++) bias2[nt] = be2[wc * 32 + nt * 16 + ln15];

  // ---- epilogue: write updated_ef (natural order, coalesced) ----
#pragma unroll
  for (int m = 0; m < 2; m++) {
#pragma unroll
    for (int r = 0; r < 4; r++) {
      int e = e0 + wr * 32 + m * 16 + q * 4 + r;
#pragma unroll
      for (int nt = 0; nt < 2; nt++) {
        int col = wc * 32 + nt * 16 + ln15;
        out_ef[(size_t)e * 128 + col] = acc2[m][nt][r] + bias2[nt];
      }
    }
  }
}

// ---------------- aggregate kernel: one wave per node, CSR gather-sum -> bf16 ----------------
__global__ __launch_bounds__(256) void agg_kernel(
    const float* __restrict__ out_ef, const int* __restrict__ cursor,
    const int* __restrict__ eidx, unsigned short* __restrict__ agg_bf) {
  const int lane = threadIdx.x & 63;
  const int wave = threadIdx.x >> 6;
  const int node = blockIdx.x * 4 + wave;
  if (node >= N_NODES) return;

  const float2* ef2 = (const float2*)out_ef;
  int s = (node == 0) ? 0 : cursor[node - 1];
  int t = cursor[node];
  float a0x=0.f,a0y=0.f,a1x=0.f,a1y=0.f,a2x=0.f,a2y=0.f,a3x=0.f,a3y=0.f;
  int j = s;
  for (; j + 8 <= t; j += 8) {   // 8 independent 512B gathers in flight per wave
    int e0v=eidx[j],   e1v=eidx[j+1], e2v=eidx[j+2], e3v=eidx[j+3];
    int e4v=eidx[j+4], e5v=eidx[j+5], e6v=eidx[j+6], e7v=eidx[j+7];
    float2 v0=ef2[(size_t)e0v*64+lane], v1=ef2[(size_t)e1v*64+lane];
    float2 v2=ef2[(size_t)e2v*64+lane], v3=ef2[(size_t)e3v*64+lane];
    float2 v4=ef2[(size_t)e4v*64+lane], v5=ef2[(size_t)e5v*64+lane];
    float2 v6=ef2[(size_t)e6v*64+lane], v7=ef2[(size_t)e7v*64+lane];
    a0x+=v0.x+v4.x; a0y+=v0.y+v4.y;
    a1x+=v1.x+v5.x; a1y+=v1.y+v5.y;
    a2x+=v2.x+v6.x; a2y+=v2.y+v6.y;
    a3x+=v3.x+v7.x; a3y+=v3.y+v7.y;
  }
  for (; j < t; ++j) {
    int ev = eidx[j];
    float2 v = ef2[(size_t)ev*64+lane];
    a0x += v.x; a0y += v.y;
  }
  float ax = (a0x + a1x) + (a2x + a3x);
  float ay = (a0y + a1y) + (a2y + a3y);
  unsigned int packed = (unsigned int)f2bf(ax) | ((unsigned int)f2bf(ay) << 16);
  *(unsigned int*)&agg_bf[(size_t)node * 128 + 2 * lane] = packed;
}

// ---------------- node kernel: stage [agg_bf | nf_bf], fused 2-layer MLP ----------------
__global__ __launch_bounds__(256, 3) void node_kernel(
    const unsigned short* __restrict__ agg_bf, const unsigned short* __restrict__ nf_bf,
    const unsigned short* __restrict__ Wn1T, const float* __restrict__ bn1,
    const unsigned short* __restrict__ Wn2T, const float* __restrict__ bn2,
    float* __restrict__ out_nf) {
  __shared__ unsigned short smem[64 * HS];   // 33792 B; h overlaid after barrier

  const int tid  = threadIdx.x;
  const int lane = tid & 63;
  const int wave = tid >> 6;
  const int ln15 = lane & 15;
  const int q    = lane >> 4;
  const int n0   = blockIdx.x * 64;

  const int nb1 = wave * 64;
  const int nb2 = wave * 32;

  float bias1[4];
#pragma unroll
  for (int nt = 0; nt < 4; nt++) bias1[nt] = bn1[nb1 + nt * 16 + ln15];

  // ---- stage nm_in = [agg_bf | nf_bf] ----
  {
#pragma unroll
    for (int i = 0; i < 4; i++) {
      int flat = tid + 256 * i;
      int row = flat >> 4, seg = flat & 15;
      int node = n0 + row;
      uint4 va = make_uint4(0u, 0u, 0u, 0u);
      uint4 vn = make_uint4(0u, 0u, 0u, 0u);
      if (node < N_NODES) {
        va = *(const uint4*)&agg_bf[(size_t)node * 128 + seg * 8];
        vn = *(const uint4*)&nf_bf[(size_t)node * 128 + seg * 8];
      }
      *(uint4*)&smem[row * HS + seg * 8] = va;
      *(uint4*)&smem[row * HS + 128 + seg * 8] = vn;
    }
  }
  __syncthreads();

  // ---- layer 1: K=256 ----
  f32x4 acc[4][4] = {};
#pragma unroll
  for (int ks = 0; ks < 8; ks++) {
    const int kc = ks * 32 + q * 8;
    bf16x8 a[4], b[4];
#pragma unroll
    for (int mt = 0; mt < 4; mt++)
      a[mt] = *(const bf16x8*)&smem[(mt * 16 + ln15) * HS + kc];
#pragma unroll
    for (int nt = 0; nt < 4; nt++)
      b[nt] = *(const bf16x8*)&Wn1T[(size_t)(nb1 + nt * 16 + ln15) * 256 + kc];
#pragma unroll
    for (int mt = 0; mt < 4; mt++)
#pragma unroll
      for (int nt = 0; nt < 4; nt++)
        acc[mt][nt] = __builtin_amdgcn_mfma_f32_16x16x32_bf16(a[mt], b[nt], acc[mt][nt], 0, 0, 0);
  }

  float bias2[2];
#pragma unroll
  for (int nt = 0; nt < 2; nt++) bias2[nt] = bn2[nb2 + nt * 16 + ln15];

  __syncthreads();

#pragma unroll
  for (int mt = 0; mt < 4; mt++)
#pragma unroll
    for (int nt = 0; nt < 4; nt++)
#pragma unroll
      for (int r = 0; r < 4; r++) {
        float v = acc[mt][nt][r] + bias1[nt];
        v = v > 0.f ? v : 0.f;
        smem[(mt * 16 + q * 4 + r) * HS + nb1 + nt * 16 + ln15] = f2bf(v);
      }
  __syncthreads();

  // ---- layer 2: K=256, N=128 ----
  f32x4 acc2[4][2] = {};
#pragma unroll
  for (int ks = 0; ks < 8; ks++) {
    const int kc = ks * 32 + q * 8;
    bf16x8 a2[4], b2[2];
#pragma unroll
    for (int mt = 0; mt < 4; mt++)
      a2[mt] = *(const bf16x8*)&smem[(mt * 16 + ln15) * HS + kc];
#pragma unroll
    for (int nt = 0; nt < 2; nt++)
      b2[nt] = *(const bf16x8*)&Wn2T[(size_t)(nb2 + nt * 16 + ln15) * 256 + kc];
#pragma unroll
    for (int mt = 0; mt < 4; mt++)
#pragma unroll
      for (int nt = 0; nt < 2; nt++)
        acc2[mt][nt] = __builtin_amdgcn_mfma_f32_16x16x32_bf16(a2[mt], b2[nt], acc2[mt][nt], 0, 0, 0);
  }

#pragma unroll
  for (int mt = 0; mt < 4; mt++) {
#pragma unroll
    for (int r = 0; r < 4; r++) {
      int row = mt * 16 + q * 4 + r;
      int node = n0 + row;
      if (node < N_NODES) {
#pragma unroll
        for (int nt = 0; nt < 2; nt++) {
          int col = nb2 + nt * 16 + ln15;
          out_nf[(size_t)node * 128 + col] = acc2[mt][nt][r] + bias2[nt];
        }
      }
    }
  }
}

extern "C" void kernel_launch(void* const* d_in, const int* in_sizes, int n_in,
                              void* d_out, int out_size, void* d_ws, size_t ws_size,
                              hipStream_t stream) {
  const float* nf  = (const float*)d_in[0];
  const float* ef  = (const float*)d_in[1];
  const int*   src = (const int*)d_in[2];
  const int*   dst = (const int*)d_in[3];
  const float* We1 = (const float*)d_in[4];
  const float* be1 = (const float*)d_in[5];
  const float* We2 = (const float*)d_in[6];
  const float* be2 = (const float*)d_in[7];
  const float* Wn1 = (const float*)d_in[8];
  const float* bn1 = (const float*)d_in[9];
  const float* Wn2 = (const float*)d_in[10];
  const float* bn2 = (const float*)d_in[11];

  float* out_nf = (float*)d_out;                    // updated_nf first (return order)
  float* out_ef = out_nf + (size_t)N_NODES * D;     // then updated_ef

  char* ws = (char*)d_ws;
  unsigned short* nf_bf  = (unsigned short*)ws;                  //  5,120,000 B
  unsigned short* We1F   = (unsigned short*)(ws + 5120000);      //    196,608 B
  unsigned short* We2F   = (unsigned short*)(ws + 5316608);      //     65,536 B
  unsigned short* Wn1T   = (unsigned short*)(ws + 5382144);      //    131,072 B
  unsigned short* Wn2T   = (unsigned short*)(ws + 5513216);      //     65,536 B
  int*            deg    = (int*)(ws + 5578752);                 //     80,000 B
  int*            cursor = (int*)(ws + 5658752);                 //     80,000 B
  int*            eidx   = (int*)(ws + 5738752);                 //  2,560,000 B
  unsigned short* agg_bf = (unsigned short*)(ws + 8298752);      //  5,120,000 B
  unsigned short* Ps     = (unsigned short*)(ws + 13418752);     // 10,240,000 B
  unsigned short* Pd     = (unsigned short*)(ws + 23658752);     // 10,240,000 B (end ~33.9 MB)

  hipMemsetAsync(deg, 0, N_NODES * sizeof(int), stream);
  prep_kernel<<<10000, 256, 0, stream>>>(nf, dst, We1, We2, Wn1, Wn2,
                                         nf_bf, We1F, We2F, Wn1T, Wn2T, deg);
  pgemm_kernel<<<(N_NODES + 63) / 64, 512, 0, stream>>>(nf_bf, We1F, be1, Ps, Pd);
  scan_kernel<<<1, 1024, 0, stream>>>(deg, cursor);
  fill_kernel<<<N_EDGES / 256, 256, 0, stream>>>(dst, cursor, eidx);
  edge_kernel<<<N_EDGES / 64, 512, 0, stream>>>(ef, Ps, Pd, src, dst,
                                                We1F, We2F, be2, out_ef);
  agg_kernel<<<N_NODES / 4, 256, 0, stream>>>(out_ef, cursor, eidx, agg_bf);
  node_kernel<<<(N_NODES + 63) / 64, 256, 0, stream>>>(agg_bf, nf_bf,
                                                       Wn1T, bn1, Wn2T, bn2, out_nf);
}